// Round 8
// baseline (880.579 us; speedup 1.0000x reference)
//
#include <hip/hip_runtime.h>
#include <stdint.h>

// ============================================================================
// CPC forward on MI355X (gfx950).
// Pipeline: k_prep (f16 weight convert + transpose, zero accumulators)
//   -> k_gemm64<256,f32A,relu>  h1 = relu(rr @ w1 + b1)            [MFMA f16]
//   -> k_enc2                   z  = l2norm(h1 @ w2 + b2)          [MFMA f16]
//   -> k_gemm64<128,f16A,->     gx = z @ W_ih^T + b_ih             [MFMA f16]
//   -> k_gru                    sequential scan, W_hh in VGPRs
//   -> k_cpc                    fused preds->l2norm->logits->online LSE/acc
//   -> k_fin                    scalar finalize
// Precision: f16 storage/operands, f32 accumulation everywhere.
// R2-R7 saga: at 768 thr (3 waves/SIMD, ~170-reg budget) the allocator always
// evicted the 128-reg W_hh row (remat from L2: 328us; scratch: 387-444us; asm
// pins: spilled-in-flight -> NaN). R8: change geometry instead of fighting.
// 256 thr/block = 1 wave/SIMD at runtime -> budget 512 regs. Thread t owns
// column t of ALL THREE gates (rows t,256+t,512+t = 384 VGPR W) -> gate math
// thread-local, ONE barrier/step, h read 32x wave-uniform ds_read_b128 reused
// for 3 dots. W re-laid-out [kchunk][row][8] for coalesced register fill.
// ~900 cyc/step expected -> ~96us.
// ============================================================================

typedef _Float16 f16;
typedef __attribute__((ext_vector_type(2))) _Float16 f16x2;
typedef __attribute__((ext_vector_type(8))) _Float16 f16x8;
typedef __attribute__((ext_vector_type(4))) float f32x4;
typedef __attribute__((ext_vector_type(4))) unsigned int u32x4;

__device__ __forceinline__ f16x2 u2h(unsigned int x) { return __builtin_bit_cast(f16x2, x); }
__device__ __forceinline__ float sigm_(float x) { return __builtin_amdgcn_rcpf(1.f + __expf(-x)); }
__device__ __forceinline__ float tanh_(float x) { return 1.f - 2.f * __builtin_amdgcn_rcpf(__expf(2.f * x) + 1.f); }

#define NTOT_LOSS 374784.0f  // 12 * 128 * 244

// ---------------------------------------------------------------------------
// K0: convert weights to f16 (transposing where consumers want), zero accum.
// whhG layout: [j=0..31][row=0..767][e=0..7]  (16B chunk j of row), so k_gru's
// per-lane 16B reads at fixed j are contiguous across lanes (coalesced 1KB).
// ---------------------------------------------------------------------------
__global__ void k_prep(const float* __restrict__ w1, const float* __restrict__ w2,
                       const float* __restrict__ wih, const float* __restrict__ whh,
                       const float* __restrict__ wkw,
                       f16* __restrict__ w1T, f16* __restrict__ w2T, f16* __restrict__ wihF,
                       f16* __restrict__ whhG, f16* __restrict__ wkT, float* __restrict__ accb) {
  const int stride = gridDim.x * blockDim.x;
  const int tid = blockIdx.x * blockDim.x + threadIdx.x;
  if (tid == 0) { accb[0] = 0.f; accb[1] = 0.f; }
  // w1 (256k x 256n) -> w1T[n][k]
  for (int i = tid; i < 65536; i += stride) { int n = i >> 8, k = i & 255; w1T[i] = (f16)w1[k * 256 + n]; }
  // w2 (256k x 128n) -> w2T[n][k]  (n<128, k<256)
  for (int i = tid; i < 32768; i += stride) { int n = i >> 8, k = i & 255; w2T[i] = (f16)w2[k * 128 + n]; }
  // W_ih (768 x 128) already [N][K] for gx GEMM
  for (int i = tid; i < 98304; i += stride) wihF[i] = (f16)wih[i];
  // W_hh (768 x 256) -> whhG[j][row][e], j = 16B k-chunk
  for (int i = tid; i < 196608; i += stride) {
    int j = i / 6144, rem = i - j * 6144, row = rem >> 3, e = rem & 7;
    whhG[i] = (f16)whh[row * 256 + j * 8 + e];
  }
  // Wk_w (12,256c,128d) -> wkT[kk][d][c]
  for (int i = tid; i < 393216; i += stride) {
    int kk = i >> 15, rem = i & 32767, d = rem >> 8, c = rem & 255;
    wkT[i] = (f16)wkw[(kk << 15) + c * 128 + d];
  }
}

// ---------------------------------------------------------------------------
// Generic 64x64-tile f16 MFMA GEMM: out[m][n] = act(A[m][:] . BT[n][:] + bias[n])
// A: [M][KTOT] (f32 or f16), BT: [N][KTOT] f16.  4 waves, wave = 16 rows x 64 cols.
// ---------------------------------------------------------------------------
template <int KTOT, bool AF32, bool RELU>
__global__ __launch_bounds__(256) void k_gemm64(const void* __restrict__ Aptr,
                                                const f16* __restrict__ BT,
                                                const float* __restrict__ bias,
                                                f16* __restrict__ out, const int NT) {
  __shared__ __align__(16) f16 Al[64][40];  // +8 pad: kills ds_read bank conflicts
  __shared__ __align__(16) f16 Bl[64][40];
  const int m0 = blockIdx.x * 64;
  const int n0 = blockIdx.y * 64;
  const int t = threadIdx.x;
  const int w = t >> 6, l = t & 63, lr = l & 15, lg = l >> 4;
  const int arow = t >> 2, akq = (t & 3) * 8;
  f32x4 acc[4] = {};
  for (int ks = 0; ks < KTOT / 32; ++ks) {
    const int kc = ks * 32;
    __syncthreads();
    if constexpr (AF32) {
      const float* src = (const float*)Aptr + (size_t)(m0 + arow) * KTOT + kc + akq;
      float4 v0 = *(const float4*)src;
      float4 v1 = *(const float4*)(src + 4);
      f16x8 hv = {(f16)v0.x, (f16)v0.y, (f16)v0.z, (f16)v0.w,
                  (f16)v1.x, (f16)v1.y, (f16)v1.z, (f16)v1.w};
      *(f16x8*)&Al[arow][akq] = hv;
    } else {
      const f16* src = (const f16*)Aptr + (size_t)(m0 + arow) * KTOT + kc + akq;
      *(f16x8*)&Al[arow][akq] = *(const f16x8*)src;
    }
    *(f16x8*)&Bl[arow][akq] = *(const f16x8*)(BT + (size_t)(n0 + arow) * KTOT + kc + akq);
    __syncthreads();
    // A-frag: row = lane&15, k = 8*(lane>>4)+j ; B-frag: col = lane&15, same k
    f16x8 af = *(const f16x8*)&Al[16 * w + lr][lg * 8];
#pragma unroll
    for (int nt = 0; nt < 4; ++nt) {
      f16x8 bf = *(const f16x8*)&Bl[nt * 16 + lr][lg * 8];
      acc[nt] = __builtin_amdgcn_mfma_f32_16x16x32_f16(af, bf, acc[nt], 0, 0, 0);
    }
  }
  // C/D: col = lane&15, row = 4*(lane>>4)+r   [m89-verified layout]
#pragma unroll
  for (int nt = 0; nt < 4; ++nt) {
    const int n = n0 + nt * 16 + lr;
    const float bb = bias[n];
#pragma unroll
    for (int r = 0; r < 4; ++r) {
      const int m = m0 + 16 * w + lg * 4 + r;
      float v = acc[nt][r] + bb;
      if (RELU) v = fmaxf(v, 0.f);
      out[(size_t)m * NT + n] = (f16)v;
    }
  }
}

// ---------------------------------------------------------------------------
// K2: z = l2norm(h1 @ w2T + b2). N=128 so each wave owns full rows -> in-wave
// shfl row-norm. Writes z f32 (output) + z f16 (workspace).
// ---------------------------------------------------------------------------
__global__ __launch_bounds__(256) void k_enc2(const f16* __restrict__ A, const f16* __restrict__ BT,
                                              const float* __restrict__ bias,
                                              float* __restrict__ zf32, f16* __restrict__ zf16) {
  __shared__ __align__(16) f16 Al[64][40];
  __shared__ __align__(16) f16 Bl[128][40];
  const int m0 = blockIdx.x * 64;
  const int t = threadIdx.x;
  const int w = t >> 6, l = t & 63, lr = l & 15, lg = l >> 4;
  const int arow = t >> 2, akq = (t & 3) * 8;
  f32x4 acc[8] = {};
  for (int ks = 0; ks < 8; ++ks) {
    const int kc = ks * 32;
    __syncthreads();
    *(f16x8*)&Al[arow][akq] = *(const f16x8*)(A + (size_t)(m0 + arow) * 256 + kc + akq);
#pragma unroll
    for (int hh = 0; hh < 2; ++hh) {
      const int brow = arow + 64 * hh;
      *(f16x8*)&Bl[brow][akq] = *(const f16x8*)(BT + (size_t)brow * 256 + kc + akq);
    }
    __syncthreads();
    f16x8 af = *(const f16x8*)&Al[16 * w + lr][lg * 8];
#pragma unroll
    for (int nt = 0; nt < 8; ++nt) {
      f16x8 bf = *(const f16x8*)&Bl[nt * 16 + lr][lg * 8];
      acc[nt] = __builtin_amdgcn_mfma_f32_16x16x32_f16(af, bf, acc[nt], 0, 0, 0);
    }
  }
  float v[8][4];
#pragma unroll
  for (int nt = 0; nt < 8; ++nt) {
    const float bb = bias[nt * 16 + lr];
#pragma unroll
    for (int r = 0; r < 4; ++r) v[nt][r] = acc[nt][r] + bb;
  }
#pragma unroll
  for (int r = 0; r < 4; ++r) {
    float ss = 0.f;
#pragma unroll
    for (int nt = 0; nt < 8; ++nt) ss += v[nt][r] * v[nt][r];
    ss += __shfl_xor(ss, 1); ss += __shfl_xor(ss, 2); ss += __shfl_xor(ss, 4); ss += __shfl_xor(ss, 8);
    const float scl = 1.f / fmaxf(sqrtf(ss), 1e-12f);
    const int m = m0 + 16 * w + lg * 4 + r;
#pragma unroll
    for (int nt = 0; nt < 8; ++nt) {
      const int n = nt * 16 + lr;
      const float z = v[nt][r] * scl;
      zf32[(size_t)m * 128 + n] = z;
      zf16[(size_t)m * 128 + n] = (f16)z;
    }
  }
}

// ---------------------------------------------------------------------------
// K4: GRU scan. 128 blocks (one batch row each) x 256 threads (= 1 wave/SIMD
// at runtime -> full 512-VGPR budget, no occupancy pressure on the allocator).
// Thread t owns COLUMN t for all three gates: W rows {t, 256+t, 512+t} =
// 96 u32x4 = 384 VGPRs, loaded once (coalesced via whhG layout). Gate math is
// thread-local (no rz exchange) -> ONE barrier per step. h broadcast:
// wave-uniform ds_read_b128 reused by all 3 row-dots. 6 fdot2 chains.
// ---------------------------------------------------------------------------
__global__ __attribute__((amdgpu_flat_work_group_size(256, 256), amdgpu_waves_per_eu(1, 1)))
void k_gru(const f16* __restrict__ gx, const f16* __restrict__ whhG,
           const float* __restrict__ bhh,
           float* __restrict__ cout, f16* __restrict__ cf16) {
  __shared__ __align__(16) f16 h_lds[2][256];
  const int b = blockIdx.x;
  const int t = threadIdx.x;  // column index
  u32x4 W[96];                // [0..31]=r row, [32..63]=z row, [64..95]=n row
  {
#pragma unroll
    for (int j = 0; j < 32; ++j)
      W[j] = *(const u32x4*)(whhG + ((size_t)j * 768 + t) * 8);
#pragma unroll
    for (int j = 0; j < 32; ++j)
      W[32 + j] = *(const u32x4*)(whhG + ((size_t)j * 768 + 256 + t) * 8);
#pragma unroll
    for (int j = 0; j < 32; ++j)
      W[64 + j] = *(const u32x4*)(whhG + ((size_t)j * 768 + 512 + t) * 8);
  }
  const float bhr = bhh[t], bhz = bhh[256 + t], bhn = bhh[512 + t];
  h_lds[0][t] = (f16)0.f;
  float h_own = 0.f;
  const f16* gxp = gx + (size_t)b * 256 * 768 + t;
  float* coutp = cout + (size_t)b * 256 * 256 + t;
  f16* cfp = cf16 + (size_t)b * 256 * 256 + t;
  __syncthreads();
#pragma unroll 1
  for (int tt = 0; tt < 256; ++tt) {
    const int cur = tt & 1;
    // issue gx loads first; ~770 cyc of fdot2 below hides their latency
    const float gxr = (float)gxp[tt * 768];
    const float gxz = (float)gxp[tt * 768 + 256];
    const float gxn = (float)gxp[tt * 768 + 512];
    float ar0 = 0.f, ar1 = 0.f, az0 = 0.f, az1 = 0.f, an0 = 0.f, an1 = 0.f;
    const u32x4* hp = (const u32x4*)(&h_lds[cur][0]);
#pragma unroll
    for (int q = 0; q < 8; ++q) {      // 8 chunks of 4x16B keeps hv window small
      u32x4 hq[4];
#pragma unroll
      for (int j = 0; j < 4; ++j) hq[j] = hp[q * 4 + j];  // wave-uniform broadcast
#pragma unroll
      for (int j = 0; j < 4; ++j) {
        const int w = q * 4 + j;
        ar0 = __builtin_amdgcn_fdot2(u2h(W[w][0]), u2h(hq[j][0]), ar0, false);
        ar1 = __builtin_amdgcn_fdot2(u2h(W[w][1]), u2h(hq[j][1]), ar1, false);
        ar0 = __builtin_amdgcn_fdot2(u2h(W[w][2]), u2h(hq[j][2]), ar0, false);
        ar1 = __builtin_amdgcn_fdot2(u2h(W[w][3]), u2h(hq[j][3]), ar1, false);
        az0 = __builtin_amdgcn_fdot2(u2h(W[32 + w][0]), u2h(hq[j][0]), az0, false);
        az1 = __builtin_amdgcn_fdot2(u2h(W[32 + w][1]), u2h(hq[j][1]), az1, false);
        az0 = __builtin_amdgcn_fdot2(u2h(W[32 + w][2]), u2h(hq[j][2]), az0, false);
        az1 = __builtin_amdgcn_fdot2(u2h(W[32 + w][3]), u2h(hq[j][3]), az1, false);
        an0 = __builtin_amdgcn_fdot2(u2h(W[64 + w][0]), u2h(hq[j][0]), an0, false);
        an1 = __builtin_amdgcn_fdot2(u2h(W[64 + w][1]), u2h(hq[j][1]), an1, false);
        an0 = __builtin_amdgcn_fdot2(u2h(W[64 + w][2]), u2h(hq[j][2]), an0, false);
        an1 = __builtin_amdgcn_fdot2(u2h(W[64 + w][3]), u2h(hq[j][3]), an1, false);
      }
    }
    const float dr = ar0 + ar1 + bhr;
    const float dz = az0 + az1 + bhz;
    const float dn = an0 + an1 + bhn;
    const float r = sigm_(gxr + dr);
    const float zz = sigm_(gxz + dz);
    const float n = tanh_(gxn + r * dn);
    const float hn = (1.f - zz) * n + zz * h_own;
    h_own = hn;
    h_lds[cur ^ 1][t] = (f16)hn;   // other buffer: no race with readers of [cur]
    coutp[tt * 256] = hn;
    cfp[tt * 256] = (f16)hn;
    __syncthreads();
  }
}

// ---------------------------------------------------------------------------
// K5: fused preds -> l2norm -> logits -> online LSE / pos / neg-max -> loss&acc.
// grid (tchunk=4, b=128, k=12), 256 threads. Never materializes logits.
// ---------------------------------------------------------------------------
__global__ __launch_bounds__(256) void k_cpc(const f16* __restrict__ cf16, const f16* __restrict__ zf16,
                                             const f16* __restrict__ wkT, const float* __restrict__ wkb,
                                             float* __restrict__ accb) {
  __shared__ __align__(16) f16 SMc[64 * 264];   // c-tile [64][264], reused as z-chunk [64][136]
  __shared__ __align__(16) f16 Bl[128][40];
  __shared__ __align__(16) f16 P[64][136];
  __shared__ float red[2];
  const int tc = blockIdx.x, b = blockIdx.y, kk = blockIdx.z;
  const int t0 = tc * 64;
  const int t = threadIdx.x;
  const int w = t >> 6, l = t & 63, lr = l & 15, lg = l >> 4;
  // ---- stage c tile (64 t-rows x 256 c = 8192 u32, 32 iters of 256) ----
  {
    const uint32_t* src = (const uint32_t*)(cf16 + ((size_t)b * 256 + t0) * 256);
    uint32_t* dst = (uint32_t*)SMc;
#pragma unroll
    for (int it = 0; it < 32; ++it) {
      const int idx = it * 256 + t, row = idx >> 7, cw = idx & 127;
      dst[row * 132 + cw] = src[row * 128 + cw];
    }
  }
  // ---- preds GEMM: (64 x 128) = c(64x256) @ WkT^T, K=256 ----
  f32x4 acc[8] = {};
  for (int ks = 0; ks < 8; ++ks) {
    __syncthreads();
    {
      const uint32_t* bsrc = (const uint32_t*)(wkT + ((size_t)kk << 15));
      uint32_t* bd = (uint32_t*)Bl;
#pragma unroll
      for (int it = 0; it < 8; ++it) {
        const int idx = it * 256 + t, row = idx >> 4, kw = idx & 15;
        bd[row * 20 + kw] = bsrc[row * 128 + ks * 16 + kw];
      }
    }
    __syncthreads();
    f16x8 af = *(const f16x8*)&SMc[(16 * w + lr) * 264 + ks * 32 + lg * 8];
#pragma unroll
    for (int nt = 0; nt < 8; ++nt) {
      f16x8 bf = *(const f16x8*)&Bl[nt * 16 + lr][lg * 8];
      acc[nt] = __builtin_amdgcn_mfma_f32_16x16x32_f16(af, bf, acc[nt], 0, 0, 0);
    }
  }
  // ---- preds epilogue: bias + row l2norm -> P (f16) ----
  {
    float v[8][4];
#pragma unroll
    for (int nt = 0; nt < 8; ++nt) {
      const float bb = wkb[kk * 128 + nt * 16 + lr];
#pragma unroll
      for (int r = 0; r < 4; ++r) v[nt][r] = acc[nt][r] + bb;
    }
#pragma unroll
    for (int r = 0; r < 4; ++r) {
      float ss = 0.f;
#pragma unroll
      for (int nt = 0; nt < 8; ++nt) ss += v[nt][r] * v[nt][r];
      ss += __shfl_xor(ss, 1); ss += __shfl_xor(ss, 2); ss += __shfl_xor(ss, 4); ss += __shfl_xor(ss, 8);
      const float scl = 1.f / fmaxf(sqrtf(ss), 1e-12f);
#pragma unroll
      for (int nt = 0; nt < 8; ++nt)
        P[16 * w + lg * 4 + r][nt * 16 + lr] = (f16)(v[nt][r] * scl);
    }
  }
  __syncthreads();
  // ---- logits + online LSE/pos/negmax over 4 s-chunks of 64 ----
  float m_run[4], s_run[4], pos_v[4], neg_m[4];
#pragma unroll
  for (int r = 0; r < 4; ++r) { m_run[r] = -1e30f; s_run[r] = 0.f; pos_v[r] = -1e30f; neg_m[r] = -1e30f; }
  for (int sc = 0; sc < 4; ++sc) {
    __syncthreads();
    {
      const uint32_t* zsrc = (const uint32_t*)(zf16 + ((size_t)b * 256 + sc * 64) * 128);
      uint32_t* zd = (uint32_t*)SMc;
#pragma unroll
      for (int it = 0; it < 16; ++it) {
        const int idx = it * 256 + t, row = idx >> 6, cw = idx & 63;
        zd[row * 68 + cw] = zsrc[row * 64 + cw];
      }
    }
    __syncthreads();
    f32x4 sa[4] = {};
#pragma unroll
    for (int ks = 0; ks < 4; ++ks) {
      f16x8 af = *(const f16x8*)&P[16 * w + lr][ks * 32 + lg * 8];
#pragma unroll
      for (int nt = 0; nt < 4; ++nt) {
        f16x8 bf = *(const f16x8*)&SMc[(nt * 16 + lr) * 136 + ks * 32 + lg * 8];
        sa[nt] = __builtin_amdgcn_mfma_f32_16x16x32_f16(af, bf, sa[nt], 0, 0, 0);
      }
    }
#pragma unroll
    for (int r = 0; r < 4; ++r) {
      const int trow = t0 + 16 * w + lg * 4 + r;
      const int pos_s = trow + kk + 1;
      float vv[4];
#pragma unroll
      for (int nt = 0; nt < 4; ++nt) vv[nt] = sa[nt][r] * 10.f;  // 1/TEMP
      float cm = fmaxf(fmaxf(vv[0], vv[1]), fmaxf(vv[2], vv[3]));
      cm = fmaxf(cm, __shfl_xor(cm, 1)); cm = fmaxf(cm, __shfl_xor(cm, 2));
      cm = fmaxf(cm, __shfl_xor(cm, 4)); cm = fmaxf(cm, __shfl_xor(cm, 8));
      const float nm = fmaxf(m_run[r], cm);
      float ps = __expf(vv[0] - nm) + __expf(vv[1] - nm) + __expf(vv[2] - nm) + __expf(vv[3] - nm);
      ps += __shfl_xor(ps, 1); ps += __shfl_xor(ps, 2); ps += __shfl_xor(ps, 4); ps += __shfl_xor(ps, 8);
      s_run[r] = s_run[r] * __expf(m_run[r] - nm) + ps;
      m_run[r] = nm;
      const int sbase = sc * 64 + lr;
#pragma unroll
      for (int nt = 0; nt < 4; ++nt) {
        const int s = sbase + nt * 16;
        if (s == pos_s) pos_v[r] = vv[nt];
        else neg_m[r] = fmaxf(neg_m[r], vv[nt]);
      }
    }
  }
  // ---- finalize ----
  __syncthreads();
  if (t == 0) { red[0] = 0.f; red[1] = 0.f; }
  __syncthreads();
  float lsum = 0.f, csum = 0.f;
#pragma unroll
  for (int r = 0; r < 4; ++r) {
    float pv = pos_v[r], ng = neg_m[r];
    pv = fmaxf(pv, __shfl_xor(pv, 1)); pv = fmaxf(pv, __shfl_xor(pv, 2));
    pv = fmaxf(pv, __shfl_xor(pv, 4)); pv = fmaxf(pv, __shfl_xor(pv, 8));
    ng = fmaxf(ng, __shfl_xor(ng, 1)); ng = fmaxf(ng, __shfl_xor(ng, 2));
    ng = fmaxf(ng, __shfl_xor(ng, 4)); ng = fmaxf(ng, __shfl_xor(ng, 8));
    const int trow = t0 + 16 * w + lg * 4 + r;
    if (lr == 0 && trow < 244) {
      const float lse = m_run[r] + __logf(s_run[r]);
      lsum += lse - pv;
      csum += (pv >= ng) ? 1.f : 0.f;
    }
  }
  if (lr == 0) { atomicAdd(&red[0], lsum); atomicAdd(&red[1], csum); }
  __syncthreads();
  if (t == 0) { atomicAdd(&accb[0], red[0]); atomicAdd(&accb[1], red[1]); }
}

__global__ void k_fin(const float* __restrict__ accb, float* __restrict__ out) {
  out[0] = accb[0] * (1.0f / NTOT_LOSS);
  out[1] = accb[1] * (100.0f / NTOT_LOSS);
}

// ---------------------------------------------------------------------------
extern "C" void kernel_launch(void* const* d_in, const int* in_sizes, int n_in,
                              void* d_out, int out_size, void* d_ws, size_t ws_size,
                              hipStream_t stream) {
  (void)in_sizes; (void)n_in; (void)out_size; (void)ws_size;
  const float* rr  = (const float*)d_in[0];
  const float* w1  = (const float*)d_in[1];
  const float* b1  = (const float*)d_in[2];
  const float* w2  = (const float*)d_in[3];
  const float* b2  = (const float*)d_in[4];
  const float* wih = (const float*)d_in[5];
  const float* whh = (const float*)d_in[6];
  const float* bih = (const float*)d_in[7];
  const float* bhh = (const float*)d_in[8];
  const float* wkw = (const float*)d_in[9];
  const float* wkb = (const float*)d_in[10];
  float* out = (float*)d_out;
  char* ws = (char*)d_ws;

  // workspace layout (77.1 MB total)
  const size_t GX_B = (size_t)32768 * 768 * 2;  // 50,331,648
  f16* gx   = (f16*)ws;
  f16* h1   = (f16*)ws;  // alias: h1 (16.8MB) dead before gx is written
  f16* zf16 = (f16*)(ws + GX_B);
  f16* cf16 = (f16*)(ws + GX_B + 8388608);
  f16* w1T  = (f16*)(ws + GX_B + 8388608 + 16777216);
  f16* w2T  = w1T + 65536;
  f16* wihF = w2T + 32768;
  f16* whhG = wihF + 98304;
  f16* wkT  = whhG + 196608;
  float* accb = (float*)(wkT + 393216);

  float* zf32 = out + 2;
  float* cf32 = out + 2 + 4194304;

  k_prep<<<256, 256, 0, stream>>>(w1, w2, wih, whh, wkw, w1T, w2T, wihF, whhG, wkT, accb);
  k_gemm64<256, true, true><<<dim3(512, 4), 256, 0, stream>>>(rr, w1T, b1, h1, 256);
  k_enc2<<<dim3(512), 256, 0, stream>>>(h1, w2T, b2, zf32, zf16);
  k_gemm64<128, false, false><<<dim3(512, 12), 256, 0, stream>>>(zf16, wihF, bih, gx, 768);
  k_gru<<<128, 256, 0, stream>>>(gx, whhG, bhh, cf32, cf16);
  k_cpc<<<dim3(4, 128, 12), 256, 0, stream>>>(cf16, zf16, wkT, wkb, accb);
  k_fin<<<1, 1, 0, stream>>>(accb, out);
}